// Round 1
// baseline (744.609 us; speedup 1.0000x reference)
//
#include <hip/hip_runtime.h>

#define NN 100000
#define NE 1600000
#define NB 98   // ceil(NN/1024)

// ---------------- graph preprocessing ----------------

__global__ void k_count(const int* __restrict__ dst, int* __restrict__ cnt) {
  int e = blockIdx.x * 256 + threadIdx.x;
  if (e < NE) atomicAdd(&cnt[dst[e]], 1);
}

__global__ void k_dinv(const int* __restrict__ cnt, float* __restrict__ dinv) {
  int i = blockIdx.x * 256 + threadIdx.x;
  if (i < NN) dinv[i] = rsqrtf(1.0f + (float)cnt[i]);  // self-loop => deg >= 1
}

__global__ void k_scan1(const int* __restrict__ cnt, int* __restrict__ rowptr,
                        int* __restrict__ bsum) {
  __shared__ int sd[256];
  const int t = threadIdx.x;
  const int base = blockIdx.x * 1024 + t * 4;
  int v0 = (base + 0 < NN) ? cnt[base + 0] : 0;
  int v1 = (base + 1 < NN) ? cnt[base + 1] : 0;
  int v2 = (base + 2 < NN) ? cnt[base + 2] : 0;
  int v3 = (base + 3 < NN) ? cnt[base + 3] : 0;
  const int s = v0 + v1 + v2 + v3;
  sd[t] = s;
  __syncthreads();
  for (int off = 1; off < 256; off <<= 1) {
    int x = (t >= off) ? sd[t - off] : 0;
    __syncthreads();
    sd[t] += x;
    __syncthreads();
  }
  if (t == 255) bsum[blockIdx.x] = sd[255];
  int run = sd[t] - s;  // exclusive within block
  if (base + 0 < NN) rowptr[base + 0] = run; run += v0;
  if (base + 1 < NN) rowptr[base + 1] = run; run += v1;
  if (base + 2 < NN) rowptr[base + 2] = run; run += v2;
  if (base + 3 < NN) rowptr[base + 3] = run;
}

__global__ void k_scan2(int* bsum) {
  if (threadIdx.x == 0 && blockIdx.x == 0) {
    int run = 0;
    for (int i = 0; i < NB; i++) { int t = bsum[i]; bsum[i] = run; run += t; }
  }
}

__global__ void k_scan3(const int* __restrict__ bsum, int* __restrict__ rowptr,
                        int* __restrict__ cursor) {
  int i = blockIdx.x * 256 + threadIdx.x;
  if (i < NN) {
    int v = rowptr[i] + bsum[i >> 10];
    rowptr[i] = v;
    cursor[i] = v;
  }
  if (i == 0) rowptr[NN] = NE;
}

__global__ void k_fill(const int* __restrict__ src, const int* __restrict__ dst,
                       int* __restrict__ cursor, int* __restrict__ col) {
  int e = blockIdx.x * 256 + threadIdx.x;
  if (e < NE) {
    int p = atomicAdd(&cursor[dst[e]], 1);
    col[p] = src[e];
  }
}

// ---------------- dense transform: hs[r] = (X[r] @ W) * dinv[r] ----------------

template <int COUT>
__global__ __launch_bounds__(256) void k_gemm(const float* __restrict__ X,
                                              const float* __restrict__ W,
                                              const float* __restrict__ dinv,
                                              float* __restrict__ hs) {
  constexpr int CT = COUT / 8;      // col-thread groups (16 or 8)
  constexpr int RT = 256 / CT;      // row-thread groups (16 or 32)
  constexpr int ROWTILE = RT * 8;   // 128 or 256
  constexpr int KC = 32;
  constexpr int KIN = 128;
  __shared__ float xs[ROWTILE][KC + 1];  // stride 33: rt-groups 8 banks apart
  __shared__ float wsh[KC][COUT];

  const int tid = threadIdx.x;
  const int ct = tid % CT;
  const int rt = tid / CT;
  const int c0 = ct * 8;
  const long rowBase = (long)blockIdx.x * ROWTILE;

  float acc[8][8];
#pragma unroll
  for (int i = 0; i < 8; i++)
#pragma unroll
    for (int j = 0; j < 8; j++) acc[i][j] = 0.0f;

  for (int kk = 0; kk < KIN; kk += KC) {
    constexpr int XF4 = ROWTILE * KC / 4;  // 1024 or 2048
#pragma unroll
    for (int q = 0; q < XF4 / 256; q++) {
      int f = tid + 256 * q;
      int r = f >> 3;            // KC/4 = 8 float4 per row
      int kq = (f & 7) << 2;
      long gr = rowBase + r;
      if (gr > NN - 1) gr = NN - 1;
      const float4 xv = *reinterpret_cast<const float4*>(X + gr * KIN + kk + kq);
      xs[r][kq + 0] = xv.x; xs[r][kq + 1] = xv.y;
      xs[r][kq + 2] = xv.z; xs[r][kq + 3] = xv.w;
    }
    constexpr int WF4 = KC * COUT / 4;  // 1024 or 512, both multiples of 256
#pragma unroll
    for (int q = 0; q < WF4 / 256; q++) {
      int f = tid + 256 * q;
      int wr = f / (COUT / 4);
      int wc = (f % (COUT / 4)) * 4;
      *reinterpret_cast<float4*>(&wsh[wr][wc]) =
          *reinterpret_cast<const float4*>(W + (long)(kk + wr) * COUT + wc);
    }
    __syncthreads();
#pragma unroll 4
    for (int k = 0; k < KC; k++) {
      const float4 w0 = *reinterpret_cast<const float4*>(&wsh[k][c0]);
      const float4 w1 = *reinterpret_cast<const float4*>(&wsh[k][c0 + 4]);
#pragma unroll
      for (int i = 0; i < 8; i++) {
        const float xv = xs[rt * 8 + i][k];
        acc[i][0] = fmaf(xv, w0.x, acc[i][0]);
        acc[i][1] = fmaf(xv, w0.y, acc[i][1]);
        acc[i][2] = fmaf(xv, w0.z, acc[i][2]);
        acc[i][3] = fmaf(xv, w0.w, acc[i][3]);
        acc[i][4] = fmaf(xv, w1.x, acc[i][4]);
        acc[i][5] = fmaf(xv, w1.y, acc[i][5]);
        acc[i][6] = fmaf(xv, w1.z, acc[i][6]);
        acc[i][7] = fmaf(xv, w1.w, acc[i][7]);
      }
    }
    __syncthreads();
  }
#pragma unroll
  for (int i = 0; i < 8; i++) {
    long r = rowBase + rt * 8 + i;
    if (r < NN) {
      float di = dinv[r];
      float4 o0 = make_float4(acc[i][0] * di, acc[i][1] * di,
                              acc[i][2] * di, acc[i][3] * di);
      float4 o1 = make_float4(acc[i][4] * di, acc[i][5] * di,
                              acc[i][6] * di, acc[i][7] * di);
      *reinterpret_cast<float4*>(hs + r * COUT + c0) = o0;
      *reinterpret_cast<float4*>(hs + r * COUT + c0 + 4) = o1;
    }
  }
}

// ---------------- aggregation: out[i] = act(dinv[i]*(hs[i] + sum_nb hs[nb]) + b) ----------------

template <int C, bool RELU>
__global__ __launch_bounds__(256) void k_agg(const float* __restrict__ hs,
                                             const int* __restrict__ rowptr,
                                             const int* __restrict__ col,
                                             const float* __restrict__ dinv,
                                             const float* __restrict__ bias,
                                             float* __restrict__ out) {
  const int gid = blockIdx.x * 256 + threadIdx.x;
  const int node = gid >> 6;  // one wave per node
  if (node >= NN) return;
  const int lane = gid & 63;
  const int beg = rowptr[node];
  const int end = rowptr[node + 1];
  if constexpr (C == 128) {
    const float* base = hs + (long)node * 128 + lane * 2;
    float ax = base[0], ay = base[1];  // self-loop contribution
    int j = beg;
    for (; j + 4 <= end; j += 4) {
      int n0 = col[j], n1 = col[j + 1], n2 = col[j + 2], n3 = col[j + 3];
      const float2 v0 = *(const float2*)(hs + (long)n0 * 128 + lane * 2);
      const float2 v1 = *(const float2*)(hs + (long)n1 * 128 + lane * 2);
      const float2 v2 = *(const float2*)(hs + (long)n2 * 128 + lane * 2);
      const float2 v3 = *(const float2*)(hs + (long)n3 * 128 + lane * 2);
      ax += (v0.x + v1.x) + (v2.x + v3.x);
      ay += (v0.y + v1.y) + (v2.y + v3.y);
    }
    for (; j < end; j++) {
      const float2 v = *(const float2*)(hs + (long)col[j] * 128 + lane * 2);
      ax += v.x; ay += v.y;
    }
    const float di = dinv[node];
    float ox = fmaf(ax, di, bias[lane * 2]);
    float oy = fmaf(ay, di, bias[lane * 2 + 1]);
    if (RELU) { ox = fmaxf(ox, 0.0f); oy = fmaxf(oy, 0.0f); }
    *(float2*)(out + (long)node * 128 + lane * 2) = make_float2(ox, oy);
  } else {
    float a = hs[(long)node * 64 + lane];
    int j = beg;
    for (; j + 4 <= end; j += 4) {
      int n0 = col[j], n1 = col[j + 1], n2 = col[j + 2], n3 = col[j + 3];
      a += (hs[(long)n0 * 64 + lane] + hs[(long)n1 * 64 + lane]) +
           (hs[(long)n2 * 64 + lane] + hs[(long)n3 * 64 + lane]);
    }
    for (; j < end; j++) a += hs[(long)col[j] * 64 + lane];
    float o = fmaf(a, dinv[node], bias[lane]);
    if (RELU) o = fmaxf(o, 0.0f);
    out[(long)node * 64 + lane] = o;
  }
}

// ---------------- launch ----------------

extern "C" void kernel_launch(void* const* d_in, const int* in_sizes, int n_in,
                              void* d_out, int out_size, void* d_ws, size_t ws_size,
                              hipStream_t stream) {
  const float* x  = (const float*)d_in[0];
  const int* ei   = (const int*)d_in[1];
  const float* W1 = (const float*)d_in[2];
  const float* b1 = (const float*)d_in[3];
  const float* W2 = (const float*)d_in[4];
  const float* b2 = (const float*)d_in[5];
  const float* W3 = (const float*)d_in[6];
  const float* b3 = (const float*)d_in[7];
  float* out = (float*)d_out;
  const int* srcp = ei;        // edge_index[0]
  const int* dstp = ei + NE;   // edge_index[1]

  char* wsb = (char*)d_ws;
  size_t off = 0;
  auto alloc = [&](size_t bytes) -> void* {
    void* p = wsb + off;
    off += (bytes + 255) & ~(size_t)255;
    return p;
  };
  float* hsA   = (float*)alloc((size_t)NN * 128 * 4);  // scaled transform
  float* hB    = (float*)alloc((size_t)NN * 128 * 4);  // aggregated activations
  int*   col   = (int*)alloc((size_t)NE * 4);
  int*   rowptr= (int*)alloc((size_t)(NN + 1) * 4);
  int*   cnt   = (int*)alloc((size_t)NN * 4);          // doubles as fill cursor
  float* dinv  = (float*)alloc((size_t)NN * 4);
  int*   bsum  = (int*)alloc((size_t)NB * 4);
  (void)ws_size; (void)in_sizes; (void)n_in; (void)out_size;

  // CSR build (once, reused by all 3 layers)
  hipMemsetAsync(cnt, 0, (size_t)NN * 4, stream);
  k_count<<<NE / 256, 256, 0, stream>>>(dstp, cnt);
  k_dinv<<<(NN + 255) / 256, 256, 0, stream>>>(cnt, dinv);
  k_scan1<<<NB, 256, 0, stream>>>(cnt, rowptr, bsum);
  k_scan2<<<1, 64, 0, stream>>>(bsum);
  k_scan3<<<(NN + 255) / 256, 256, 0, stream>>>(bsum, rowptr, cnt);
  k_fill<<<NE / 256, 256, 0, stream>>>(srcp, dstp, cnt, col);

  const int aggGrid = (NN * 64) / 256;  // 25000 exactly

  // layer 1
  k_gemm<128><<<(NN + 127) / 128, 256, 0, stream>>>(x, W1, dinv, hsA);
  k_agg<128, true><<<aggGrid, 256, 0, stream>>>(hsA, rowptr, col, dinv, b1, hB);
  // layer 2
  k_gemm<128><<<(NN + 127) / 128, 256, 0, stream>>>(hB, W2, dinv, hsA);
  k_agg<128, true><<<aggGrid, 256, 0, stream>>>(hsA, rowptr, col, dinv, b2, hB);
  // layer 3 (128 -> 64, no relu)
  k_gemm<64><<<(NN + 255) / 256, 256, 0, stream>>>(hB, W3, dinv, hsA);
  k_agg<64, false><<<aggGrid, 256, 0, stream>>>(hsA, rowptr, col, dinv, b3, out);
}

// Round 2
// 635.126 us; speedup vs baseline: 1.1724x; 1.1724x over previous
//
#include <hip/hip_runtime.h>

#define NN 100000
#define NE 1600000
#define NB 98    // ceil(NN/1024) — scan blocks AND node-buckets
#define NBK 98   // buckets of 1024 nodes
#define BSH 10   // bucket = dst >> 10

// ---------------- bucketed CSR build ----------------

__global__ void k_hist(const int* __restrict__ dst, int* __restrict__ bucketCnt) {
  __shared__ int lc[NBK];
  const int t = threadIdx.x;
  for (int i = t; i < NBK; i += 256) lc[i] = 0;
  __syncthreads();
  const int base = blockIdx.x * 4096;
#pragma unroll
  for (int q = 0; q < 16; q++) {
    int e = base + t + 256 * q;
    if (e < NE) atomicAdd(&lc[dst[e] >> BSH], 1);
  }
  __syncthreads();
  for (int i = t; i < NBK; i += 256)
    if (lc[i]) atomicAdd(&bucketCnt[i], lc[i]);
}

__global__ void k_scanb(const int* __restrict__ bucketCnt, int* __restrict__ bucketBase,
                        int* __restrict__ bucketCursor) {
  if (threadIdx.x == 0) {
    int run = 0;
    for (int i = 0; i < NBK; i++) {
      bucketBase[i] = run;
      bucketCursor[i] = run;
      run += bucketCnt[i];
    }
    bucketBase[NBK] = run;  // == NE
  }
}

// Partial sort of edges into 1024-node buckets: coalesced pair writes.
__global__ __launch_bounds__(256) void k_scatter(const int* __restrict__ src,
                                                 const int* __restrict__ dst,
                                                 int* __restrict__ bucketCursor,
                                                 unsigned long long* __restrict__ pairArr) {
  __shared__ int lcnt[NBK];
  __shared__ int lbase[NBK];
  __shared__ int lrank[NBK];
  __shared__ int bbase[NBK];
  __shared__ unsigned long long sorted[4096];
  __shared__ int target[4096];
  const int t = threadIdx.x;
  for (int i = t; i < NBK; i += 256) { lcnt[i] = 0; lrank[i] = 0; }
  __syncthreads();
  const int base = blockIdx.x * 4096;
  int rs[16], rd[16];
#pragma unroll
  for (int q = 0; q < 16; q++) {
    int e = base + t + 256 * q;
    rs[q] = (e < NE) ? src[e] : -1;
    rd[q] = (e < NE) ? dst[e] : -1;
    if (rd[q] >= 0) atomicAdd(&lcnt[rd[q] >> BSH], 1);
  }
  __syncthreads();
  if (t == 0) {
    int run = 0;
    for (int i = 0; i < NBK; i++) { lbase[i] = run; run += lcnt[i]; }
  }
  __syncthreads();
  if (t < NBK && lcnt[t] > 0) bbase[t] = atomicAdd(&bucketCursor[t], lcnt[t]);
  __syncthreads();
#pragma unroll
  for (int q = 0; q < 16; q++) {
    if (rd[q] >= 0) {
      int b = rd[q] >> BSH;
      int r = atomicAdd(&lrank[b], 1);
      int slot = lbase[b] + r;
      sorted[slot] = ((unsigned long long)(unsigned)rs[q] << 32) | (unsigned)rd[q];
      target[slot] = bbase[b] + r;
    }
  }
  __syncthreads();
  const int n = min(4096, NE - base);
  // consecutive slots -> consecutive targets within bucket runs: coalesced
  for (int s = t; s < n; s += 256) pairArr[target[s]] = sorted[s];
}

// One block per bucket: per-node counts via LDS atomics, plus dinv.
__global__ void k_cntdinv(const unsigned long long* __restrict__ pairArr,
                          const int* __restrict__ bucketBase,
                          int* __restrict__ cnt, float* __restrict__ dinv) {
  __shared__ int lc[1024];
  const int t = threadIdx.x;
  const int b = blockIdx.x;
  for (int i = t; i < 1024; i += 256) lc[i] = 0;
  __syncthreads();
  const int ebeg = bucketBase[b], eend = bucketBase[b + 1];
  const int n0 = b << BSH;
  for (int i = ebeg + t; i < eend; i += 256) {
    int d = (int)(unsigned)(pairArr[i] & 0xffffffffULL);
    atomicAdd(&lc[d - n0], 1);
  }
  __syncthreads();
  for (int i = t; i < 1024; i += 256) {
    int node = n0 + i;
    if (node < NN) {
      cnt[node] = lc[i];
      dinv[node] = rsqrtf(1.0f + (float)lc[i]);  // self-loop => deg >= 1
    }
  }
}

// One block per bucket: col writes confined to one ~64KB window, one XCD.
__global__ void k_csrfill(const unsigned long long* __restrict__ pairArr,
                          const int* __restrict__ bucketBase,
                          const int* __restrict__ rowptr,
                          int* __restrict__ col) {
  __shared__ int curs[1024];
  const int t = threadIdx.x;
  const int b = blockIdx.x;
  const int n0 = b << BSH;
  for (int i = t; i < 1024; i += 256) {
    int node = n0 + i;
    curs[i] = (node < NN) ? rowptr[node] : 0;
  }
  __syncthreads();
  const int ebeg = bucketBase[b], eend = bucketBase[b + 1];
  for (int i = ebeg + t; i < eend; i += 256) {
    unsigned long long p = pairArr[i];
    int d = (int)(unsigned)(p & 0xffffffffULL);
    int s = (int)(unsigned)(p >> 32);
    int pos = atomicAdd(&curs[d - n0], 1);
    col[pos] = s;
  }
}

// ---------------- rowptr scan ----------------

__global__ void k_scan1(const int* __restrict__ cnt, int* __restrict__ rowptr,
                        int* __restrict__ bsum) {
  __shared__ int sd[256];
  const int t = threadIdx.x;
  const int base = blockIdx.x * 1024 + t * 4;
  int v0 = (base + 0 < NN) ? cnt[base + 0] : 0;
  int v1 = (base + 1 < NN) ? cnt[base + 1] : 0;
  int v2 = (base + 2 < NN) ? cnt[base + 2] : 0;
  int v3 = (base + 3 < NN) ? cnt[base + 3] : 0;
  const int s = v0 + v1 + v2 + v3;
  sd[t] = s;
  __syncthreads();
  for (int off = 1; off < 256; off <<= 1) {
    int x = (t >= off) ? sd[t - off] : 0;
    __syncthreads();
    sd[t] += x;
    __syncthreads();
  }
  if (t == 255) bsum[blockIdx.x] = sd[255];
  int run = sd[t] - s;  // exclusive within block
  if (base + 0 < NN) rowptr[base + 0] = run; run += v0;
  if (base + 1 < NN) rowptr[base + 1] = run; run += v1;
  if (base + 2 < NN) rowptr[base + 2] = run; run += v2;
  if (base + 3 < NN) rowptr[base + 3] = run;
}

__global__ void k_scan2(int* bsum) {
  if (threadIdx.x == 0 && blockIdx.x == 0) {
    int run = 0;
    for (int i = 0; i < NB; i++) { int t = bsum[i]; bsum[i] = run; run += t; }
  }
}

__global__ void k_scan3(const int* __restrict__ bsum, int* __restrict__ rowptr) {
  int i = blockIdx.x * 256 + threadIdx.x;
  if (i < NN) rowptr[i] = rowptr[i] + bsum[i >> 10];
  if (i == 0) rowptr[NN] = NE;
}

// ---------------- dense transform: hs[r] = (X[r] @ W) * dinv[r] ----------------

template <int COUT>
__global__ __launch_bounds__(256) void k_gemm(const float* __restrict__ X,
                                              const float* __restrict__ W,
                                              const float* __restrict__ dinv,
                                              float* __restrict__ hs) {
  constexpr int CT = COUT / 8;      // col-thread groups (16 or 8)
  constexpr int RT = 256 / CT;      // row-thread groups (16 or 32)
  constexpr int ROWTILE = RT * 8;   // 128 or 256
  constexpr int KC = 32;
  constexpr int KIN = 128;
  __shared__ float xs[ROWTILE][KC + 1];
  __shared__ float wsh[KC][COUT];

  const int tid = threadIdx.x;
  const int ct = tid % CT;
  const int rt = tid / CT;
  const int c0 = ct * 8;
  const long rowBase = (long)blockIdx.x * ROWTILE;

  float acc[8][8];
#pragma unroll
  for (int i = 0; i < 8; i++)
#pragma unroll
    for (int j = 0; j < 8; j++) acc[i][j] = 0.0f;

  for (int kk = 0; kk < KIN; kk += KC) {
    constexpr int XF4 = ROWTILE * KC / 4;
#pragma unroll
    for (int q = 0; q < XF4 / 256; q++) {
      int f = tid + 256 * q;
      int r = f >> 3;
      int kq = (f & 7) << 2;
      long gr = rowBase + r;
      if (gr > NN - 1) gr = NN - 1;
      const float4 xv = *reinterpret_cast<const float4*>(X + gr * KIN + kk + kq);
      xs[r][kq + 0] = xv.x; xs[r][kq + 1] = xv.y;
      xs[r][kq + 2] = xv.z; xs[r][kq + 3] = xv.w;
    }
    constexpr int WF4 = KC * COUT / 4;
#pragma unroll
    for (int q = 0; q < WF4 / 256; q++) {
      int f = tid + 256 * q;
      int wr = f / (COUT / 4);
      int wc = (f % (COUT / 4)) * 4;
      *reinterpret_cast<float4*>(&wsh[wr][wc]) =
          *reinterpret_cast<const float4*>(W + (long)(kk + wr) * COUT + wc);
    }
    __syncthreads();
#pragma unroll 4
    for (int k = 0; k < KC; k++) {
      const float4 w0 = *reinterpret_cast<const float4*>(&wsh[k][c0]);
      const float4 w1 = *reinterpret_cast<const float4*>(&wsh[k][c0 + 4]);
#pragma unroll
      for (int i = 0; i < 8; i++) {
        const float xv = xs[rt * 8 + i][k];
        acc[i][0] = fmaf(xv, w0.x, acc[i][0]);
        acc[i][1] = fmaf(xv, w0.y, acc[i][1]);
        acc[i][2] = fmaf(xv, w0.z, acc[i][2]);
        acc[i][3] = fmaf(xv, w0.w, acc[i][3]);
        acc[i][4] = fmaf(xv, w1.x, acc[i][4]);
        acc[i][5] = fmaf(xv, w1.y, acc[i][5]);
        acc[i][6] = fmaf(xv, w1.z, acc[i][6]);
        acc[i][7] = fmaf(xv, w1.w, acc[i][7]);
      }
    }
    __syncthreads();
  }
#pragma unroll
  for (int i = 0; i < 8; i++) {
    long r = rowBase + rt * 8 + i;
    if (r < NN) {
      float di = dinv[r];
      float4 o0 = make_float4(acc[i][0] * di, acc[i][1] * di,
                              acc[i][2] * di, acc[i][3] * di);
      float4 o1 = make_float4(acc[i][4] * di, acc[i][5] * di,
                              acc[i][6] * di, acc[i][7] * di);
      *reinterpret_cast<float4*>(hs + r * COUT + c0) = o0;
      *reinterpret_cast<float4*>(hs + r * COUT + c0 + 4) = o1;
    }
  }
}

// ---------------- aggregation ----------------

template <int C, bool RELU>
__global__ __launch_bounds__(256) void k_agg(const float* __restrict__ hs,
                                             const int* __restrict__ rowptr,
                                             const int* __restrict__ col,
                                             const float* __restrict__ dinv,
                                             const float* __restrict__ bias,
                                             float* __restrict__ out) {
  const int gid = blockIdx.x * 256 + threadIdx.x;
  const int node = gid >> 6;  // one wave per node
  if (node >= NN) return;
  const int lane = gid & 63;
  const int beg = rowptr[node];
  const int end = rowptr[node + 1];
  if constexpr (C == 128) {
    const float* base = hs + (long)node * 128 + lane * 2;
    float ax = base[0], ay = base[1];  // self-loop
    int j = beg;
    for (; j + 4 <= end; j += 4) {
      int n0 = col[j], n1 = col[j + 1], n2 = col[j + 2], n3 = col[j + 3];
      const float2 v0 = *(const float2*)(hs + (long)n0 * 128 + lane * 2);
      const float2 v1 = *(const float2*)(hs + (long)n1 * 128 + lane * 2);
      const float2 v2 = *(const float2*)(hs + (long)n2 * 128 + lane * 2);
      const float2 v3 = *(const float2*)(hs + (long)n3 * 128 + lane * 2);
      ax += (v0.x + v1.x) + (v2.x + v3.x);
      ay += (v0.y + v1.y) + (v2.y + v3.y);
    }
    for (; j < end; j++) {
      const float2 v = *(const float2*)(hs + (long)col[j] * 128 + lane * 2);
      ax += v.x; ay += v.y;
    }
    const float di = dinv[node];
    float ox = fmaf(ax, di, bias[lane * 2]);
    float oy = fmaf(ay, di, bias[lane * 2 + 1]);
    if (RELU) { ox = fmaxf(ox, 0.0f); oy = fmaxf(oy, 0.0f); }
    *(float2*)(out + (long)node * 128 + lane * 2) = make_float2(ox, oy);
  } else {
    float a = hs[(long)node * 64 + lane];
    int j = beg;
    for (; j + 4 <= end; j += 4) {
      int n0 = col[j], n1 = col[j + 1], n2 = col[j + 2], n3 = col[j + 3];
      a += (hs[(long)n0 * 64 + lane] + hs[(long)n1 * 64 + lane]) +
           (hs[(long)n2 * 64 + lane] + hs[(long)n3 * 64 + lane]);
    }
    for (; j < end; j++) a += hs[(long)col[j] * 64 + lane];
    float o = fmaf(a, dinv[node], bias[lane]);
    if (RELU) o = fmaxf(o, 0.0f);
    out[(long)node * 64 + lane] = o;
  }
}

// ---------------- launch ----------------

extern "C" void kernel_launch(void* const* d_in, const int* in_sizes, int n_in,
                              void* d_out, int out_size, void* d_ws, size_t ws_size,
                              hipStream_t stream) {
  const float* x  = (const float*)d_in[0];
  const int* ei   = (const int*)d_in[1];
  const float* W1 = (const float*)d_in[2];
  const float* b1 = (const float*)d_in[3];
  const float* W2 = (const float*)d_in[4];
  const float* b2 = (const float*)d_in[5];
  const float* W3 = (const float*)d_in[6];
  const float* b3 = (const float*)d_in[7];
  float* out = (float*)d_out;
  const int* srcp = ei;        // edge_index[0]
  const int* dstp = ei + NE;   // edge_index[1]

  char* wsb = (char*)d_ws;
  size_t off = 0;
  auto alloc = [&](size_t bytes) -> void* {
    void* p = wsb + off;
    off += (bytes + 255) & ~(size_t)255;
    return p;
  };
  float* hsA    = (float*)alloc((size_t)NN * 128 * 4);  // scaled transform
  float* hB     = (float*)alloc((size_t)NN * 128 * 4);  // aggregated activations
  int*   col    = (int*)alloc((size_t)NE * 4);
  int*   rowptr = (int*)alloc((size_t)(NN + 1) * 4);
  int*   cnt    = (int*)alloc((size_t)NN * 4);
  float* dinv   = (float*)alloc((size_t)NN * 4);
  int*   bsum   = (int*)alloc((size_t)NB * 4);
  int*   bucketCnt    = (int*)alloc((size_t)NBK * 4);
  int*   bucketBase   = (int*)alloc((size_t)(NBK + 1) * 4);
  int*   bucketCursor = (int*)alloc((size_t)NBK * 4);
  // pairArr aliases hsA: only live during CSR build, before layer 1's gemm.
  unsigned long long* pairArr = (unsigned long long*)hsA;
  (void)ws_size; (void)in_sizes; (void)n_in; (void)out_size;

  const int SCB = (NE + 4095) / 4096;  // 391 blocks for hist/scatter

  hipMemsetAsync(bucketCnt, 0, (size_t)NBK * 4, stream);
  k_hist<<<SCB, 256, 0, stream>>>(dstp, bucketCnt);
  k_scanb<<<1, 64, 0, stream>>>(bucketCnt, bucketBase, bucketCursor);
  k_scatter<<<SCB, 256, 0, stream>>>(srcp, dstp, bucketCursor, pairArr);
  k_cntdinv<<<NBK, 256, 0, stream>>>(pairArr, bucketBase, cnt, dinv);
  k_scan1<<<NB, 256, 0, stream>>>(cnt, rowptr, bsum);
  k_scan2<<<1, 64, 0, stream>>>(bsum);
  k_scan3<<<(NN + 255) / 256, 256, 0, stream>>>(bsum, rowptr);
  k_csrfill<<<NBK, 256, 0, stream>>>(pairArr, bucketBase, rowptr, col);

  const int aggGrid = (NN * 64) / 256;  // 25000 exactly

  // layer 1
  k_gemm<128><<<(NN + 127) / 128, 256, 0, stream>>>(x, W1, dinv, hsA);
  k_agg<128, true><<<aggGrid, 256, 0, stream>>>(hsA, rowptr, col, dinv, b1, hB);
  // layer 2
  k_gemm<128><<<(NN + 127) / 128, 256, 0, stream>>>(hB, W2, dinv, hsA);
  k_agg<128, true><<<aggGrid, 256, 0, stream>>>(hsA, rowptr, col, dinv, b2, hB);
  // layer 3 (128 -> 64, no relu)
  k_gemm<64><<<(NN + 255) / 256, 256, 0, stream>>>(hB, W3, dinv, hsA);
  k_agg<64, false><<<aggGrid, 256, 0, stream>>>(hsA, rowptr, col, dinv, b3, out);
}

// Round 3
// 626.223 us; speedup vs baseline: 1.1890x; 1.0142x over previous
//
#include <hip/hip_runtime.h>

#define NN 100000
#define NE 1600000
#define NB 98    // ceil(NN/1024) — scan blocks AND node-buckets
#define NBK 98   // buckets of 1024 nodes
#define BSH 10   // bucket = dst >> 10

// ---------------- bucketed CSR build ----------------

__global__ void k_hist(const int* __restrict__ dst, int* __restrict__ bucketCnt) {
  __shared__ int lc[NBK];
  const int t = threadIdx.x;
  for (int i = t; i < NBK; i += 256) lc[i] = 0;
  __syncthreads();
  const int base = blockIdx.x * 4096;
#pragma unroll
  for (int q = 0; q < 16; q++) {
    int e = base + t + 256 * q;
    if (e < NE) atomicAdd(&lc[dst[e] >> BSH], 1);
  }
  __syncthreads();
  for (int i = t; i < NBK; i += 256)
    if (lc[i]) atomicAdd(&bucketCnt[i], lc[i]);
}

__global__ void k_scanb(const int* __restrict__ bucketCnt, int* __restrict__ bucketBase,
                        int* __restrict__ bucketCursor) {
  if (threadIdx.x == 0) {
    int run = 0;
    for (int i = 0; i < NBK; i++) {
      bucketBase[i] = run;
      bucketCursor[i] = run;
      run += bucketCnt[i];
    }
    bucketBase[NBK] = run;  // == NE
  }
}

// Partial sort of edges into 1024-node buckets: coalesced pair writes.
__global__ __launch_bounds__(256) void k_scatter(const int* __restrict__ src,
                                                 const int* __restrict__ dst,
                                                 int* __restrict__ bucketCursor,
                                                 unsigned long long* __restrict__ pairArr) {
  __shared__ int lcnt[NBK];
  __shared__ int lbase[NBK];
  __shared__ int lrank[NBK];
  __shared__ int bbase[NBK];
  __shared__ unsigned long long sorted[4096];
  __shared__ int target[4096];
  const int t = threadIdx.x;
  for (int i = t; i < NBK; i += 256) { lcnt[i] = 0; lrank[i] = 0; }
  __syncthreads();
  const int base = blockIdx.x * 4096;
  int rs[16], rd[16];
#pragma unroll
  for (int q = 0; q < 16; q++) {
    int e = base + t + 256 * q;
    rs[q] = (e < NE) ? src[e] : -1;
    rd[q] = (e < NE) ? dst[e] : -1;
    if (rd[q] >= 0) atomicAdd(&lcnt[rd[q] >> BSH], 1);
  }
  __syncthreads();
  if (t == 0) {
    int run = 0;
    for (int i = 0; i < NBK; i++) { lbase[i] = run; run += lcnt[i]; }
  }
  __syncthreads();
  if (t < NBK && lcnt[t] > 0) bbase[t] = atomicAdd(&bucketCursor[t], lcnt[t]);
  __syncthreads();
#pragma unroll
  for (int q = 0; q < 16; q++) {
    if (rd[q] >= 0) {
      int b = rd[q] >> BSH;
      int r = atomicAdd(&lrank[b], 1);
      int slot = lbase[b] + r;
      sorted[slot] = ((unsigned long long)(unsigned)rs[q] << 32) | (unsigned)rd[q];
      target[slot] = bbase[b] + r;
    }
  }
  __syncthreads();
  const int n = min(4096, NE - base);
  for (int s = t; s < n; s += 256) pairArr[target[s]] = sorted[s];
}

// One block per bucket: per-node counts via LDS atomics, plus dinv.
__global__ void k_cntdinv(const unsigned long long* __restrict__ pairArr,
                          const int* __restrict__ bucketBase,
                          int* __restrict__ cnt, float* __restrict__ dinv) {
  __shared__ int lc[1024];
  const int t = threadIdx.x;
  const int b = blockIdx.x;
  for (int i = t; i < 1024; i += 256) lc[i] = 0;
  __syncthreads();
  const int ebeg = bucketBase[b], eend = bucketBase[b + 1];
  const int n0 = b << BSH;
  for (int i = ebeg + t; i < eend; i += 256) {
    int d = (int)(unsigned)(pairArr[i] & 0xffffffffULL);
    atomicAdd(&lc[d - n0], 1);
  }
  __syncthreads();
  for (int i = t; i < 1024; i += 256) {
    int node = n0 + i;
    if (node < NN) {
      cnt[node] = lc[i];
      dinv[node] = rsqrtf(1.0f + (float)lc[i]);  // self-loop => deg >= 1
    }
  }
}

// One block per bucket: col writes confined to one ~64KB window, one XCD.
__global__ void k_csrfill(const unsigned long long* __restrict__ pairArr,
                          const int* __restrict__ bucketBase,
                          const int* __restrict__ rowptr,
                          int* __restrict__ col) {
  __shared__ int curs[1024];
  const int t = threadIdx.x;
  const int b = blockIdx.x;
  const int n0 = b << BSH;
  for (int i = t; i < 1024; i += 256) {
    int node = n0 + i;
    curs[i] = (node < NN) ? rowptr[node] : 0;
  }
  __syncthreads();
  const int ebeg = bucketBase[b], eend = bucketBase[b + 1];
  for (int i = ebeg + t; i < eend; i += 256) {
    unsigned long long p = pairArr[i];
    int d = (int)(unsigned)(p & 0xffffffffULL);
    int s = (int)(unsigned)(p >> 32);
    int pos = atomicAdd(&curs[d - n0], 1);
    col[pos] = s;
  }
}

// ---------------- rowptr scan ----------------

__global__ void k_scan1(const int* __restrict__ cnt, int* __restrict__ rowptr,
                        int* __restrict__ bsum) {
  __shared__ int sd[256];
  const int t = threadIdx.x;
  const int base = blockIdx.x * 1024 + t * 4;
  int v0 = (base + 0 < NN) ? cnt[base + 0] : 0;
  int v1 = (base + 1 < NN) ? cnt[base + 1] : 0;
  int v2 = (base + 2 < NN) ? cnt[base + 2] : 0;
  int v3 = (base + 3 < NN) ? cnt[base + 3] : 0;
  const int s = v0 + v1 + v2 + v3;
  sd[t] = s;
  __syncthreads();
  for (int off = 1; off < 256; off <<= 1) {
    int x = (t >= off) ? sd[t - off] : 0;
    __syncthreads();
    sd[t] += x;
    __syncthreads();
  }
  if (t == 255) bsum[blockIdx.x] = sd[255];
  int run = sd[t] - s;
  if (base + 0 < NN) rowptr[base + 0] = run; run += v0;
  if (base + 1 < NN) rowptr[base + 1] = run; run += v1;
  if (base + 2 < NN) rowptr[base + 2] = run; run += v2;
  if (base + 3 < NN) rowptr[base + 3] = run;
}

__global__ void k_scan2(int* bsum) {
  if (threadIdx.x == 0 && blockIdx.x == 0) {
    int run = 0;
    for (int i = 0; i < NB; i++) { int t = bsum[i]; bsum[i] = run; run += t; }
  }
}

__global__ void k_scan3(const int* __restrict__ bsum, int* __restrict__ rowptr) {
  int i = blockIdx.x * 256 + threadIdx.x;
  if (i < NN) rowptr[i] = rowptr[i] + bsum[i >> 10];
  if (i == 0) rowptr[NN] = NE;
}

// ---------------- dense transform: hs[r] = (X[r] @ W) * dinv[r] ----------------

template <int COUT>
__global__ __launch_bounds__(256) void k_gemm(const float* __restrict__ X,
                                              const float* __restrict__ W,
                                              const float* __restrict__ dinv,
                                              float* __restrict__ hs) {
  constexpr int CT = COUT / 8;
  constexpr int RT = 256 / CT;
  constexpr int ROWTILE = RT * 8;
  constexpr int KC = 32;
  constexpr int KIN = 128;
  __shared__ float xs[ROWTILE][KC + 1];
  __shared__ float wsh[KC][COUT];

  const int tid = threadIdx.x;
  const int ct = tid % CT;
  const int rt = tid / CT;
  const int c0 = ct * 8;
  const long rowBase = (long)blockIdx.x * ROWTILE;

  float acc[8][8];
#pragma unroll
  for (int i = 0; i < 8; i++)
#pragma unroll
    for (int j = 0; j < 8; j++) acc[i][j] = 0.0f;

  for (int kk = 0; kk < KIN; kk += KC) {
    constexpr int XF4 = ROWTILE * KC / 4;
#pragma unroll
    for (int q = 0; q < XF4 / 256; q++) {
      int f = tid + 256 * q;
      int r = f >> 3;
      int kq = (f & 7) << 2;
      long gr = rowBase + r;
      if (gr > NN - 1) gr = NN - 1;
      const float4 xv = *reinterpret_cast<const float4*>(X + gr * KIN + kk + kq);
      xs[r][kq + 0] = xv.x; xs[r][kq + 1] = xv.y;
      xs[r][kq + 2] = xv.z; xs[r][kq + 3] = xv.w;
    }
    constexpr int WF4 = KC * COUT / 4;
#pragma unroll
    for (int q = 0; q < WF4 / 256; q++) {
      int f = tid + 256 * q;
      int wr = f / (COUT / 4);
      int wc = (f % (COUT / 4)) * 4;
      *reinterpret_cast<float4*>(&wsh[wr][wc]) =
          *reinterpret_cast<const float4*>(W + (long)(kk + wr) * COUT + wc);
    }
    __syncthreads();
#pragma unroll 4
    for (int k = 0; k < KC; k++) {
      const float4 w0 = *reinterpret_cast<const float4*>(&wsh[k][c0]);
      const float4 w1 = *reinterpret_cast<const float4*>(&wsh[k][c0 + 4]);
#pragma unroll
      for (int i = 0; i < 8; i++) {
        const float xv = xs[rt * 8 + i][k];
        acc[i][0] = fmaf(xv, w0.x, acc[i][0]);
        acc[i][1] = fmaf(xv, w0.y, acc[i][1]);
        acc[i][2] = fmaf(xv, w0.z, acc[i][2]);
        acc[i][3] = fmaf(xv, w0.w, acc[i][3]);
        acc[i][4] = fmaf(xv, w1.x, acc[i][4]);
        acc[i][5] = fmaf(xv, w1.y, acc[i][5]);
        acc[i][6] = fmaf(xv, w1.z, acc[i][6]);
        acc[i][7] = fmaf(xv, w1.w, acc[i][7]);
      }
    }
    __syncthreads();
  }
#pragma unroll
  for (int i = 0; i < 8; i++) {
    long r = rowBase + rt * 8 + i;
    if (r < NN) {
      float di = dinv[r];
      float4 o0 = make_float4(acc[i][0] * di, acc[i][1] * di,
                              acc[i][2] * di, acc[i][3] * di);
      float4 o1 = make_float4(acc[i][4] * di, acc[i][5] * di,
                              acc[i][6] * di, acc[i][7] * di);
      *reinterpret_cast<float4*>(hs + r * COUT + c0) = o0;
      *reinterpret_cast<float4*>(hs + r * COUT + c0 + 4) = o1;
    }
  }
}

// ---------------- aggregation ----------------
// 128-ch: half-wave (32 lanes) covers one row via float4; one load instr
// fetches TWO rows (1 KB); unrolled x4 -> 8 rows (4 KB) in flight per wave,
// with next-group col prefetch to hide the index->row dependency.

template <bool RELU>
__global__ __launch_bounds__(256) void k_agg128(const float* __restrict__ hs,
                                                const int* __restrict__ rowptr,
                                                const int* __restrict__ col,
                                                const float* __restrict__ dinv,
                                                const float* __restrict__ bias,
                                                float* __restrict__ out) {
  const int gid = blockIdx.x * 256 + threadIdx.x;
  const int node = gid >> 6;  // one wave per node (uniform across wave)
  if (node >= NN) return;
  const int lane = threadIdx.x & 63;
  const int half = lane >> 5;
  const int ch = (lane & 31) * 4;
  const int beg = rowptr[node];
  const int end = rowptr[node + 1];

  float4 acc;
  if (half == 0) {
    acc = *reinterpret_cast<const float4*>(hs + (long)node * 128 + ch);  // self
  } else {
    acc = make_float4(0.f, 0.f, 0.f, 0.f);
  }

  int j = beg;
  if (j + 8 <= end) {
    int c0 = col[j + 0 + half];
    int c1 = col[j + 2 + half];
    int c2 = col[j + 4 + half];
    int c3 = col[j + 6 + half];
    while (true) {
      const float4 v0 = *reinterpret_cast<const float4*>(hs + (long)c0 * 128 + ch);
      const float4 v1 = *reinterpret_cast<const float4*>(hs + (long)c1 * 128 + ch);
      const float4 v2 = *reinterpret_cast<const float4*>(hs + (long)c2 * 128 + ch);
      const float4 v3 = *reinterpret_cast<const float4*>(hs + (long)c3 * 128 + ch);
      j += 8;
      const bool more = (j + 8 <= end);
      int n0, n1, n2, n3;
      if (more) {
        n0 = col[j + 0 + half];
        n1 = col[j + 2 + half];
        n2 = col[j + 4 + half];
        n3 = col[j + 6 + half];
      }
      acc.x += (v0.x + v1.x) + (v2.x + v3.x);
      acc.y += (v0.y + v1.y) + (v2.y + v3.y);
      acc.z += (v0.z + v1.z) + (v2.z + v3.z);
      acc.w += (v0.w + v1.w) + (v2.w + v3.w);
      if (!more) break;
      c0 = n0; c1 = n1; c2 = n2; c3 = n3;
    }
  }
  for (; j + 2 <= end; j += 2) {
    int c = col[j + half];
    const float4 v = *reinterpret_cast<const float4*>(hs + (long)c * 128 + ch);
    acc.x += v.x; acc.y += v.y; acc.z += v.z; acc.w += v.w;
  }
  if (j < end && half == 0) {
    int c = col[j];
    const float4 v = *reinterpret_cast<const float4*>(hs + (long)c * 128 + ch);
    acc.x += v.x; acc.y += v.y; acc.z += v.z; acc.w += v.w;
  }

  // combine the two half-wave partials (lane l <-> l^32)
  acc.x += __shfl(acc.x, lane ^ 32);
  acc.y += __shfl(acc.y, lane ^ 32);
  acc.z += __shfl(acc.z, lane ^ 32);
  acc.w += __shfl(acc.w, lane ^ 32);

  if (half == 0) {
    const float di = dinv[node];
    const float4 b = *reinterpret_cast<const float4*>(bias + ch);
    float4 o;
    o.x = fmaf(acc.x, di, b.x);
    o.y = fmaf(acc.y, di, b.y);
    o.z = fmaf(acc.z, di, b.z);
    o.w = fmaf(acc.w, di, b.w);
    if (RELU) {
      o.x = fmaxf(o.x, 0.f); o.y = fmaxf(o.y, 0.f);
      o.z = fmaxf(o.z, 0.f); o.w = fmaxf(o.w, 0.f);
    }
    *reinterpret_cast<float4*>(out + (long)node * 128 + ch) = o;
  }
}

// 64-ch: quarter-wave (16 lanes) covers one row via float4; one load instr
// fetches FOUR rows (1 KB).

__global__ __launch_bounds__(256) void k_agg64(const float* __restrict__ hs,
                                               const int* __restrict__ rowptr,
                                               const int* __restrict__ col,
                                               const float* __restrict__ dinv,
                                               const float* __restrict__ bias,
                                               float* __restrict__ out) {
  const int gid = blockIdx.x * 256 + threadIdx.x;
  const int node = gid >> 6;
  if (node >= NN) return;
  const int lane = threadIdx.x & 63;
  const int quarter = lane >> 4;
  const int ch = (lane & 15) * 4;
  const int beg = rowptr[node];
  const int end = rowptr[node + 1];

  float4 acc;
  if (quarter == 0) {
    acc = *reinterpret_cast<const float4*>(hs + (long)node * 64 + ch);  // self
  } else {
    acc = make_float4(0.f, 0.f, 0.f, 0.f);
  }

  int j = beg;
  if (j + 8 <= end) {
    int c0 = col[j + 0 + quarter];
    int c1 = col[j + 4 + quarter];
    while (true) {
      const float4 v0 = *reinterpret_cast<const float4*>(hs + (long)c0 * 64 + ch);
      const float4 v1 = *reinterpret_cast<const float4*>(hs + (long)c1 * 64 + ch);
      j += 8;
      const bool more = (j + 8 <= end);
      int n0, n1;
      if (more) {
        n0 = col[j + 0 + quarter];
        n1 = col[j + 4 + quarter];
      }
      acc.x += v0.x + v1.x;
      acc.y += v0.y + v1.y;
      acc.z += v0.z + v1.z;
      acc.w += v0.w + v1.w;
      if (!more) break;
      c0 = n0; c1 = n1;
    }
  }
  for (; j + 4 <= end; j += 4) {
    int c = col[j + quarter];
    const float4 v = *reinterpret_cast<const float4*>(hs + (long)c * 64 + ch);
    acc.x += v.x; acc.y += v.y; acc.z += v.z; acc.w += v.w;
  }
  {
    const int r = end - j;  // 0..3 leftover edges
    if (quarter < r) {
      int c = col[j + quarter];
      const float4 v = *reinterpret_cast<const float4*>(hs + (long)c * 64 + ch);
      acc.x += v.x; acc.y += v.y; acc.z += v.z; acc.w += v.w;
    }
  }

  // combine four quarter-wave partials: butterfly over lane^32, lane^16
  acc.x += __shfl(acc.x, lane ^ 32);
  acc.y += __shfl(acc.y, lane ^ 32);
  acc.z += __shfl(acc.z, lane ^ 32);
  acc.w += __shfl(acc.w, lane ^ 32);
  acc.x += __shfl(acc.x, lane ^ 16);
  acc.y += __shfl(acc.y, lane ^ 16);
  acc.z += __shfl(acc.z, lane ^ 16);
  acc.w += __shfl(acc.w, lane ^ 16);

  if (quarter == 0) {
    const float di = dinv[node];
    const float4 b = *reinterpret_cast<const float4*>(bias + ch);
    float4 o;
    o.x = fmaf(acc.x, di, b.x);
    o.y = fmaf(acc.y, di, b.y);
    o.z = fmaf(acc.z, di, b.z);
    o.w = fmaf(acc.w, di, b.w);
    *reinterpret_cast<float4*>(out + (long)node * 64 + ch) = o;
  }
}

// ---------------- launch ----------------

extern "C" void kernel_launch(void* const* d_in, const int* in_sizes, int n_in,
                              void* d_out, int out_size, void* d_ws, size_t ws_size,
                              hipStream_t stream) {
  const float* x  = (const float*)d_in[0];
  const int* ei   = (const int*)d_in[1];
  const float* W1 = (const float*)d_in[2];
  const float* b1 = (const float*)d_in[3];
  const float* W2 = (const float*)d_in[4];
  const float* b2 = (const float*)d_in[5];
  const float* W3 = (const float*)d_in[6];
  const float* b3 = (const float*)d_in[7];
  float* out = (float*)d_out;
  const int* srcp = ei;        // edge_index[0]
  const int* dstp = ei + NE;   // edge_index[1]

  char* wsb = (char*)d_ws;
  size_t off = 0;
  auto alloc = [&](size_t bytes) -> void* {
    void* p = wsb + off;
    off += (bytes + 255) & ~(size_t)255;
    return p;
  };
  float* hsA    = (float*)alloc((size_t)NN * 128 * 4);
  float* hB     = (float*)alloc((size_t)NN * 128 * 4);
  int*   col    = (int*)alloc((size_t)NE * 4);
  int*   rowptr = (int*)alloc((size_t)(NN + 1) * 4);
  int*   cnt    = (int*)alloc((size_t)NN * 4);
  float* dinv   = (float*)alloc((size_t)NN * 4);
  int*   bsum   = (int*)alloc((size_t)NB * 4);
  int*   bucketCnt    = (int*)alloc((size_t)NBK * 4);
  int*   bucketBase   = (int*)alloc((size_t)(NBK + 1) * 4);
  int*   bucketCursor = (int*)alloc((size_t)NBK * 4);
  unsigned long long* pairArr = (unsigned long long*)hsA;  // aliases hsA (build-only)
  (void)ws_size; (void)in_sizes; (void)n_in; (void)out_size;

  const int SCB = (NE + 4095) / 4096;

  hipMemsetAsync(bucketCnt, 0, (size_t)NBK * 4, stream);
  k_hist<<<SCB, 256, 0, stream>>>(dstp, bucketCnt);
  k_scanb<<<1, 64, 0, stream>>>(bucketCnt, bucketBase, bucketCursor);
  k_scatter<<<SCB, 256, 0, stream>>>(srcp, dstp, bucketCursor, pairArr);
  k_cntdinv<<<NBK, 256, 0, stream>>>(pairArr, bucketBase, cnt, dinv);
  k_scan1<<<NB, 256, 0, stream>>>(cnt, rowptr, bsum);
  k_scan2<<<1, 64, 0, stream>>>(bsum);
  k_scan3<<<(NN + 255) / 256, 256, 0, stream>>>(bsum, rowptr);
  k_csrfill<<<NBK, 256, 0, stream>>>(pairArr, bucketBase, rowptr, col);

  const int aggGrid = (NN * 64) / 256;  // 25000

  // layer 1
  k_gemm<128><<<(NN + 127) / 128, 256, 0, stream>>>(x, W1, dinv, hsA);
  k_agg128<true><<<aggGrid, 256, 0, stream>>>(hsA, rowptr, col, dinv, b1, hB);
  // layer 2
  k_gemm<128><<<(NN + 127) / 128, 256, 0, stream>>>(hB, W2, dinv, hsA);
  k_agg128<true><<<aggGrid, 256, 0, stream>>>(hsA, rowptr, col, dinv, b2, hB);
  // layer 3 (128 -> 64, no relu)
  k_gemm<64><<<(NN + 255) / 256, 256, 0, stream>>>(hB, W3, dinv, hsA);
  k_agg64<<<aggGrid, 256, 0, stream>>>(hsA, rowptr, col, dinv, b3, out);
}